// Round 3
// baseline (802.973 us; speedup 1.0000x reference)
//
#include <hip/hip_runtime.h>

typedef _Float16 h16;
typedef _Float16 h16x8 __attribute__((ext_vector_type(8)));
typedef float    f32x4 __attribute__((ext_vector_type(4)));
typedef unsigned long long u64;

static constexpr int NN  = 32768;
static constexpr int EE  = 262144;
static constexpr int TT  = 262144;
static constexpr int D   = 128;   // DN = DE
static constexpr int K3  = 640;   // 3*DN + 2*DE
static constexpr int LDA = 72;    // padded LDS stride for c2final (64 + 8)
#define EPS 1e-5f

// async global->LDS DMA, 16 B/lane: lane l writes lds_base + l*16
__device__ __forceinline__ void async16(const void* g, void* l) {
    __builtin_amdgcn_global_load_lds(
        (const __attribute__((address_space(1))) unsigned int*)g,
        (__attribute__((address_space(3))) unsigned int*)l, 16, 0, 0);
}

// ---------------------------------------------------------------------------
// fp32 -> fp16 converter, 8 elems/thread
// ---------------------------------------------------------------------------
__global__ __launch_bounds__(256) void cvt_f32_f16(
    const float* __restrict__ src, h16* __restrict__ dst, int n8)
{
    const int i = blockIdx.x * 256 + threadIdx.x;
    if (i >= n8) return;
    const float4* s = reinterpret_cast<const float4*>(src);
    const float4 a = s[2 * i], b = s[2 * i + 1];
    h16x8 o;
    o[0] = (h16)a.x; o[1] = (h16)a.y; o[2] = (h16)a.z; o[3] = (h16)a.w;
    o[4] = (h16)b.x; o[5] = (h16)b.y; o[6] = (h16)b.z; o[7] = (h16)b.w;
    *reinterpret_cast<h16x8*>(dst + 8 * i) = o;
}

// ---------------------------------------------------------------------------
// c3: gathered A [T,640](fp16) @ W3^T [640,256](fp16) + b3 -> LN(256) ->
// sigmoid*tanh -> atomicAdd into acc3[E,128] (fp32, = d_out).
// Pipeline: Kc=32 (20 chunks), double-buffered LDS, ALL staging via
// global_load_lds (width 16), ONE barrier per chunk, prefetch issued
// post-barrier so its vmcnt isn't drained until the NEXT barrier.
// LDS layout: packed 64-B rows, granule position p = g ^ ((row>>1)&3)
// (swizzle applied on the DMA's per-lane global address) -> 2-way banks.
// ---------------------------------------------------------------------------
__global__ __launch_bounds__(256, 3) void c3_kernel(
    const h16* __restrict__ nodeh, const h16* __restrict__ edgeh,
    const int* __restrict__ idx_i, const int* __restrict__ idx_j,
    const int* __restrict__ idx_k, const int* __restrict__ idx_ji,
    const int* __restrict__ idx_kj,
    const h16* __restrict__ W3h, const float* __restrict__ b3,
    const float* __restrict__ g3, const float* __restrict__ be3,
    float* __restrict__ acc3)
{
    __shared__ h16 As[2 * 128 * 32];   // 16 KB (double-buffered)
    __shared__ h16 Bs[2 * 256 * 32];   // 32 KB

    const int tid  = threadIdx.x;
    const int lane = tid & 63;
    const int wave = tid >> 6;
    const int l15  = lane & 15;
    const int quad = lane >> 4;
    const int m0   = blockIdx.x * 128;

    // DMA lane constants: lane l stages row base+(l>>2), LDS granule l&3;
    // source granule g = (l&3) ^ s(row), s(row) = (row>>1)&3 = (l>>3)&3.
    const int lr   = lane >> 2;
    const int gswz = (((lane & 3) ^ ((lane >> 3) & 3)) << 4);  // byte offset

    // A-gather indices: 5 segs x 2 sub-blocks of 16 rows per wave
    const int ra0 = m0 + wave * 32 + lr, ra1 = ra0 + 16;
    const int ix0a = idx_i[ra0],  ix0b = idx_i[ra1];
    const int ix1a = idx_j[ra0],  ix1b = idx_j[ra1];
    const int ix2a = idx_k[ra0],  ix2b = idx_k[ra1];
    const int ix3a = idx_ji[ra0], ix3b = idx_ji[ra1];
    const int ix4a = idx_kj[ra0], ix4b = idx_kj[ra1];

    f32x4 acc[2][16];
    #pragma unroll
    for (int mt = 0; mt < 2; ++mt)
        #pragma unroll
        for (int nt = 0; nt < 16; ++nt)
            acc[mt][nt] = (f32x4){0.f, 0.f, 0.f, 0.f};

    const char* nb = (const char*)nodeh;
    const char* eb = (const char*)edgeh;
    const char* wb = (const char*)W3h;
    const int browbase = wave * 64 + lr;   // B staging rows per wave: +q*16

    auto dma_chunk = [&](int c) {
        const int buf = c & 1;
        h16* Asb = &As[buf * 4096];
        h16* Bsb = &Bs[buf * 8192];
        const int seg = c >> 2;
        const int ia = seg == 0 ? ix0a : seg == 1 ? ix1a : seg == 2 ? ix2a
                     : seg == 3 ? ix3a : ix4a;
        const int ib = seg == 0 ? ix0b : seg == 1 ? ix1b : seg == 2 ? ix2b
                     : seg == 3 ? ix3b : ix4b;
        const char* src = (seg < 3) ? nb : eb;
        const int co = (c & 3) * 64;   // 32 h16 per chunk within the 128-wide seg
        async16(src + (u64)ia * 256 + co + gswz, &Asb[(wave * 32) * 32]);
        async16(src + (u64)ib * 256 + co + gswz, &Asb[(wave * 32 + 16) * 32]);
        const int cb = c * 64;         // chunk offset within W3 row (1280 B)
        #pragma unroll
        for (int q = 0; q < 4; ++q) {
            const int roff = (browbase + q * 16) * 1280 + gswz + cb;
            async16(wb + roff, &Bsb[(wave * 64 + q * 16) * 32]);
        }
    };

    dma_chunk(0);

    // fragment read offsets (h16 elems): row*32 + p*8, p = quad ^ ((l15>>1)&3)
    const int p8    = ((quad ^ ((l15 >> 1) & 3)) << 3);
    const int abase = (wave * 32 + l15) * 32 + p8;
    const int bbase = l15 * 32 + p8;

    #pragma unroll 1
    for (int c = 0; c < 20; ++c) {
        __syncthreads();               // drains DMA(c) + all chunk c-1 LDS reads
        if (c + 1 < 20) dma_chunk(c + 1);
        const h16* Asb = &As[(c & 1) * 4096];
        const h16* Bsb = &Bs[(c & 1) * 8192];
        h16x8 a0 = *(const h16x8*)&Asb[abase];
        h16x8 a1 = *(const h16x8*)&Asb[abase + 512];
        #pragma unroll
        for (int nt = 0; nt < 16; ++nt) {
            h16x8 b = *(const h16x8*)&Bsb[bbase + nt * 512];
            acc[0][nt] = __builtin_amdgcn_mfma_f32_16x16x32_f16(a0, b, acc[0][nt], 0, 0, 0);
            acc[1][nt] = __builtin_amdgcn_mfma_f32_16x16x32_f16(a1, b, acc[1][nt], 0, 0, 0);
        }
    }

    // ---- epilogue: +b3, LN(256), gate, atomic scatter ----
    float bias[16], gg[16], bb[16];
    #pragma unroll
    for (int nt = 0; nt < 16; ++nt) {
        const int cc = nt * 16 + l15;
        bias[nt] = b3[cc]; gg[nt] = g3[cc]; bb[nt] = be3[cc];
    }
    #pragma unroll
    for (int mt = 0; mt < 2; ++mt) {
        #pragma unroll
        for (int rg = 0; rg < 4; ++rg) {
            float v[16];
            float s = 0.f, s2 = 0.f;
            #pragma unroll
            for (int nt = 0; nt < 16; ++nt) {
                v[nt] = acc[mt][nt][rg] + bias[nt];
                s += v[nt]; s2 += v[nt] * v[nt];
            }
            #pragma unroll
            for (int m = 1; m < 16; m <<= 1) {
                s  += __shfl_xor(s,  m, 64);
                s2 += __shfl_xor(s2, m, 64);
            }
            const float mean = s * (1.f / 256.f);
            const float var  = s2 * (1.f / 256.f) - mean * mean;
            const float inv  = rsqrtf(var + EPS);
            const int rowg   = m0 + wave * 32 + mt * 16 + quad * 4 + rg;
            const size_t e   = (size_t)idx_ji[rowg];
            #pragma unroll
            for (int nt = 0; nt < 8; ++nt) {
                const float f   = (v[nt]     - mean) * inv * gg[nt]     + bb[nt];
                const float co  = (v[nt + 8] - mean) * inv * gg[nt + 8] + bb[nt + 8];
                const float msg = (1.f / (1.f + __expf(-f))) * tanhf(co);
                atomicAdd(&acc3[e * D + nt * 16 + l15], msg);
            }
        }
    }
}

// ---------------------------------------------------------------------------
// c2final: (node[i]*node[j]) @ W2^T + b2 -> LN(256) -> gate -> LN(128) = c2
// then c3 = LN(128)(acc3 row), out = tanh(edge + c2 + c3), in place in d_out.
// ---------------------------------------------------------------------------
__global__ __launch_bounds__(256, 2) void c2final_kernel(
    const h16* __restrict__ nodeh,
    const int* __restrict__ ei, const int* __restrict__ ej,
    const h16* __restrict__ W2h, const float* __restrict__ b2,
    const float* __restrict__ g2, const float* __restrict__ be2,
    const float* __restrict__ g22, const float* __restrict__ be22,
    const float* __restrict__ g32, const float* __restrict__ be32,
    const float* __restrict__ edge, float* __restrict__ out)
{
    __shared__ h16 As[128 * LDA];
    __shared__ h16 Bs[256 * LDA];

    const int tid  = threadIdx.x;
    const int lane = tid & 63;
    const int wave = tid >> 6;
    const int l15  = lane & 15;
    const int quad = lane >> 4;
    const int m0   = blockIdx.x * 128;

    f32x4 acc[2][16];
    #pragma unroll
    for (int mt = 0; mt < 2; ++mt)
        #pragma unroll
        for (int nt = 0; nt < 16; ++nt)
            acc[mt][nt] = (f32x4){0.f, 0.f, 0.f, 0.f};

    const int r = tid >> 1;
    const int h = tid & 1;
    const size_t ri = (size_t)ei[m0 + r];
    const size_t rj = (size_t)ej[m0 + r];

    #pragma unroll 1
    for (int c = 0; c < 2; ++c) {
        const h16x8* si = reinterpret_cast<const h16x8*>(nodeh + ri * D + c * 64 + h * 32);
        const h16x8* sj = reinterpret_cast<const h16x8*>(nodeh + rj * D + c * 64 + h * 32);
        h16x8 av[4];
        #pragma unroll
        for (int q = 0; q < 4; ++q) av[q] = si[q] * sj[q];
        const h16x8* wp = reinterpret_cast<const h16x8*>(W2h + (size_t)tid * D + c * 64);
        h16x8 bv[8];
        #pragma unroll
        for (int q = 0; q < 8; ++q) bv[q] = wp[q];

        __syncthreads();
        h16x8* ad = reinterpret_cast<h16x8*>(&As[r * LDA + h * 32]);
        #pragma unroll
        for (int q = 0; q < 4; ++q) ad[q] = av[q];
        h16x8* bd = reinterpret_cast<h16x8*>(&Bs[tid * LDA]);
        #pragma unroll
        for (int q = 0; q < 8; ++q) bd[q] = bv[q];
        __syncthreads();

        #pragma unroll
        for (int kk = 0; kk < 64; kk += 32) {
            h16x8 a0 = *reinterpret_cast<const h16x8*>(&As[(wave*32      + l15) * LDA + kk + quad*8]);
            h16x8 a1 = *reinterpret_cast<const h16x8*>(&As[(wave*32 + 16 + l15) * LDA + kk + quad*8]);
            #pragma unroll
            for (int nt = 0; nt < 16; ++nt) {
                h16x8 b = *reinterpret_cast<const h16x8*>(&Bs[(nt*16 + l15) * LDA + kk + quad*8]);
                acc[0][nt] = __builtin_amdgcn_mfma_f32_16x16x32_f16(a0, b, acc[0][nt], 0, 0, 0);
                acc[1][nt] = __builtin_amdgcn_mfma_f32_16x16x32_f16(a1, b, acc[1][nt], 0, 0, 0);
            }
        }
    }

    // ---- epilogue ----
    float bias[16], gg[16], bb[16];
    #pragma unroll
    for (int nt = 0; nt < 16; ++nt) {
        const int cc = nt * 16 + l15;
        bias[nt] = b2[cc]; gg[nt] = g2[cc]; bb[nt] = be2[cc];
    }
    float g2c[8], b2c[8], g3c[8], b3c[8];
    #pragma unroll
    for (int nt = 0; nt < 8; ++nt) {
        const int cc = nt * 16 + l15;
        g2c[nt] = g22[cc]; b2c[nt] = be22[cc];
        g3c[nt] = g32[cc]; b3c[nt] = be32[cc];
    }
    #pragma unroll
    for (int mt = 0; mt < 2; ++mt) {
        #pragma unroll
        for (int rg = 0; rg < 4; ++rg) {
            float v[16];
            float s = 0.f, s2 = 0.f;
            #pragma unroll
            for (int nt = 0; nt < 16; ++nt) {
                v[nt] = acc[mt][nt][rg] + bias[nt];
                s += v[nt]; s2 += v[nt] * v[nt];
            }
            #pragma unroll
            for (int m = 1; m < 16; m <<= 1) {
                s  += __shfl_xor(s,  m, 64);
                s2 += __shfl_xor(s2, m, 64);
            }
            const float mean = s * (1.f / 256.f);
            const float var  = s2 * (1.f / 256.f) - mean * mean;
            const float inv  = rsqrtf(var + EPS);
            float msg[8];
            float t = 0.f, t2 = 0.f;
            #pragma unroll
            for (int nt = 0; nt < 8; ++nt) {
                const float f  = (v[nt]     - mean) * inv * gg[nt]     + bb[nt];
                const float co = (v[nt + 8] - mean) * inv * gg[nt + 8] + bb[nt + 8];
                const float m_ = (1.f / (1.f + __expf(-f))) * tanhf(co);
                msg[nt] = m_; t += m_; t2 += m_ * m_;
            }
            #pragma unroll
            for (int m = 1; m < 16; m <<= 1) {
                t  += __shfl_xor(t,  m, 64);
                t2 += __shfl_xor(t2, m, 64);
            }
            const float mean2 = t * (1.f / 128.f);
            const float var2  = t2 * (1.f / 128.f) - mean2 * mean2;
            const float inv2  = rsqrtf(var2 + EPS);

            // ---- c3 LN over the scattered sum (in d_out), then combine ----
            const size_t e = (size_t)(m0 + wave * 32 + mt * 16 + quad * 4 + rg);
            float a3[8];
            float sa = 0.f, sa2 = 0.f;
            #pragma unroll
            for (int nt = 0; nt < 8; ++nt) {
                a3[nt] = out[e * D + nt * 16 + l15];
                sa += a3[nt]; sa2 += a3[nt] * a3[nt];
            }
            #pragma unroll
            for (int m = 1; m < 16; m <<= 1) {
                sa  += __shfl_xor(sa,  m, 64);
                sa2 += __shfl_xor(sa2, m, 64);
            }
            const float mean3 = sa * (1.f / 128.f);
            const float var3  = sa2 * (1.f / 128.f) - mean3 * mean3;
            const float inv3  = rsqrtf(var3 + EPS);
            #pragma unroll
            for (int nt = 0; nt < 8; ++nt) {
                const float c2v = (msg[nt] - mean2) * inv2 * g2c[nt] + b2c[nt];
                const float c3v = (a3[nt]  - mean3) * inv3 * g3c[nt] + b3c[nt];
                const float ev  = edge[e * D + nt * 16 + l15];
                out[e * D + nt * 16 + l15] = tanhf(ev + c2v + c3v);
            }
        }
    }
}

// ---------------------------------------------------------------------------
extern "C" void kernel_launch(void* const* d_in, const int* in_sizes, int n_in,
                              void* d_out, int out_size, void* d_ws, size_t ws_size,
                              hipStream_t stream)
{
    const float* node   = (const float*)d_in[0];
    const float* edge   = (const float*)d_in[1];
    const int*   e_i    = (const int*)d_in[2];
    const int*   e_j    = (const int*)d_in[3];
    const int*   idx_i  = (const int*)d_in[4];
    const int*   idx_j  = (const int*)d_in[5];
    const int*   idx_k  = (const int*)d_in[6];
    const int*   idx_ji = (const int*)d_in[7];
    const int*   idx_kj = (const int*)d_in[8];
    const float* W2     = (const float*)d_in[9];
    const float* b2     = (const float*)d_in[10];
    const float* W3     = (const float*)d_in[11];
    const float* b3     = (const float*)d_in[12];
    const float* g_c2   = (const float*)d_in[13];
    const float* be_c2  = (const float*)d_in[14];
    const float* g_c3   = (const float*)d_in[15];
    const float* be_c3  = (const float*)d_in[16];
    const float* g_c22  = (const float*)d_in[17];
    const float* be_c22 = (const float*)d_in[18];
    const float* g_c32  = (const float*)d_in[19];
    const float* be_c32 = (const float*)d_in[20];

    // ws layout (fp16): W3h [256*640] | W2h [256*128] | nodeh [N*128] | edgeh [E*128]
    h16* W3h   = (h16*)d_ws;
    h16* W2h   = W3h + 256 * K3;
    h16* nodeh = W2h + 256 * D;
    h16* edgeh = nodeh + (size_t)NN * D;
    float* acc3 = (float*)d_out;   // fp32 scatter accumulator, finalized in place
    float* out  = (float*)d_out;

    hipMemsetAsync(d_out, 0, (size_t)EE * D * sizeof(float), stream);
    cvt_f32_f16<<<dim3((256 * K3 / 8 + 255) / 256), dim3(256), 0, stream>>>(W3, W3h, 256 * K3 / 8);
    cvt_f32_f16<<<dim3((256 * D  / 8 + 255) / 256), dim3(256), 0, stream>>>(W2, W2h, 256 * D / 8);
    cvt_f32_f16<<<dim3((NN * D   / 8 + 255) / 256), dim3(256), 0, stream>>>(node, nodeh, NN * D / 8);
    cvt_f32_f16<<<dim3(((int)((size_t)EE * D / 8) + 255) / 256), dim3(256), 0, stream>>>(edge, edgeh, (int)((size_t)EE * D / 8));

    c3_kernel<<<dim3(TT / 128), dim3(256), 0, stream>>>(
        nodeh, edgeh, idx_i, idx_j, idx_k, idx_ji, idx_kj, W3h, b3, g_c3, be_c3, acc3);
    c2final_kernel<<<dim3(EE / 128), dim3(256), 0, stream>>>(
        nodeh, e_i, e_j, W2h, b2, g_c2, be_c2, g_c22, be_c22, g_c32, be_c32, edge, out);
}